// Round 8
// baseline (51.135 us; speedup 1.0000x reference)
//
#include <hip/hip_runtime.h>

#define BATCH 64
#define TLEN  2048
#define DDIM  256
#define ADIM  128
#define TM    64          // t-rows per tile
#define TILES 4           // tiles per block
#define EPSC  1e-7f

typedef __bf16 bf16x8 __attribute__((ext_vector_type(8)));
typedef float  f32x4  __attribute__((ext_vector_type(4)));

// DPP-based add of a lane-permuted copy (VALU pipe, not LDS)
template <int CTRL>
__device__ __forceinline__ float dpp_add(float v) {
    int vi = __builtin_bit_cast(int, v);
    int sw = __builtin_amdgcn_update_dpp(vi, vi, CTRL, 0xF, 0xF, false);
    return v + __builtin_bit_cast(float, sw);
}

// raw workgroup barrier: orders LDS only, leaves global loads (vmcnt) in flight
__device__ __forceinline__ void bar_lds() {
    asm volatile("s_waitcnt lgkmcnt(0)" ::: "memory");
    __builtin_amdgcn_s_barrier();
}

// ws layout:
//   [0,     65536)  : N   f32[16384]  (unnormalized numerator, per b,d)
//   [65536, 65792)  : s   f32[64]     (unnormalized denominator, per b)
//   [65792, 66048)  : cnt int[64]     (blocks-done counter, per b)
// all zeroed by hipMemsetAsync at launch.

__global__ __launch_bounds__(256, 2) void attn_main(const float* __restrict__ x,
                                                    const float* __restrict__ W,
                                                    const float* __restrict__ bias,
                                                    const float* __restrict__ u,
                                                    float* __restrict__ N,
                                                    float* __restrict__ s,
                                                    int* __restrict__ cnt,
                                                    float* __restrict__ out) {
    __shared__ char  xs[2][TM * DDIM * 2];   // 2 x 32 KB, XOR-swizzled 16B blocks
    __shared__ float wpart[4][TM];           // per-wave 32-col row partials
    __shared__ float wlds[TM];               // exp(z) per row of current tile
    __shared__ float fpart[4][32][8];        // pooling partials (4 KB)
    __shared__ float sv_lds;
    __shared__ int   flag_lds;

    const int b    = blockIdx.x >> 3;            // 8 blocks per batch
    const int t00  = (blockIdx.x & 7) * (TILES * TM);
    const int tid  = threadIdx.x;
    const int wave = tid >> 6;
    const int lane = tid & 63;
    const int lm   = lane & 15;                  // col index within 16x16 C tile
    const int lk   = lane >> 4;                  // k-block / row-quad index
    const int row  = wave * 16 + lm;             // local row this thread stages

    const float* xbase = x + ((size_t)(b * TLEN + t00 + row)) * DDIM;

    // ---- prologue: issue tile-0 x loads FIRST (longest latency) ----
    f32x4 fa[8], fb[8];
#pragma unroll
    for (int kt = 0; kt < 8; ++kt) {
        fa[kt] = *(const f32x4*)(xbase + kt * 32 + lk * 8);
        fb[kt] = *(const f32x4*)(xbase + kt * 32 + lk * 8 + 4);
    }

    // ---- build W fragments directly from global (L2-hit; hides under x loads)
    // B-frag for mfma_16x16x32: lane(lm,lk) holds col=wave*32+ntl*16+lm,
    // k = kt*32 + lk*8 + j
    bf16x8 wfreg[8][2];
#pragma unroll
    for (int kt = 0; kt < 8; ++kt)
#pragma unroll
        for (int ntl = 0; ntl < 2; ++ntl) {
            const float* wp = W + (size_t)(kt * 32 + lk * 8) * ADIM + wave * 32 + ntl * 16 + lm;
            bf16x8 w;
#pragma unroll
            for (int j = 0; j < 8; ++j) w[j] = (__bf16)wp[j * ADIM];
            wfreg[kt][ntl] = w;
        }

    // wave w owns A-columns [w*32, w*32+32)
    float bias_r[2], u_r[2];
#pragma unroll
    for (int ntl = 0; ntl < 2; ++ntl) {
        bias_r[ntl] = bias[wave * 32 + ntl * 16 + lm];
        u_r[ntl]    = u[wave * 32 + ntl * 16 + lm];
    }

    float vacc[8] = {0.f, 0.f, 0.f, 0.f, 0.f, 0.f, 0.f, 0.f};
    float sreg = 0.f;
    const int dgrp = tid & 31;     // pooling: d = dgrp*8 + j
    const int tgrp = tid >> 5;     // pooling: t = tgrp*8 + i

    for (int it = 0; it < TILES; ++it) {
        char* buf = xs[it & 1];

        // ---- cvt + stash current tile (consumes fa/fb) ----
#pragma unroll
        for (int kt = 0; kt < 8; ++kt) {
            bf16x8 a;
#pragma unroll
            for (int i = 0; i < 4; ++i) { a[i] = (__bf16)fa[kt][i]; a[4 + i] = (__bf16)fb[kt][i]; }
            *(bf16x8*)(buf + ((row * 512 + (kt * 32 + lk * 8) * 2) ^ ((row & 7) << 4))) = a;
        }

        // ---- issue next tile's loads BEFORE the barrier: in flight across the
        //      whole tile (raw barriers below never drain vmcnt) ----
        if (it + 1 < TILES) {
            const float* xn = xbase + (size_t)(it + 1) * TM * DDIM;
#pragma unroll
            for (int kt = 0; kt < 8; ++kt) {
                fa[kt] = *(const f32x4*)(xn + kt * 32 + lk * 8);
                fb[kt] = *(const f32x4*)(xn + kt * 32 + lk * 8 + 4);
            }
        }
        bar_lds();   // stash visible to all waves; prefetch NOT drained

        // ---- GEMM: 64 rows x 32 cols per wave, A-frags from LDS, W from regs ----
        f32x4 acc[4][2];
#pragma unroll
        for (int m = 0; m < 4; ++m)
#pragma unroll
            for (int ntl = 0; ntl < 2; ++ntl) acc[m][ntl] = (f32x4){0.f, 0.f, 0.f, 0.f};

#pragma unroll
        for (int kt = 0; kt < 8; ++kt) {
#pragma unroll
            for (int m = 0; m < 4; ++m) {
                const int r = m * 16 + lm;
                bf16x8 afrag = *(const bf16x8*)(buf + ((r * 512 + (kt * 32 + lk * 8) * 2) ^ ((r & 7) << 4)));
                acc[m][0] = __builtin_amdgcn_mfma_f32_16x16x32_bf16(afrag, wfreg[kt][0], acc[m][0], 0, 0, 0);
                acc[m][1] = __builtin_amdgcn_mfma_f32_16x16x32_bf16(afrag, wfreg[kt][1], acc[m][1], 0, 0, 0);
            }
        }

        // ---- logits -> per-wave 32-col partial row sums (DPP, VALU pipe) ----
#pragma unroll
        for (int m = 0; m < 4; ++m) {
#pragma unroll
            for (int reg = 0; reg < 4; ++reg) {
                float p = 0.f;
#pragma unroll
                for (int ntl = 0; ntl < 2; ++ntl) {
                    float lg = acc[m][ntl][reg] + bias_r[ntl];
                    float e  = __expf(2.0f * lg);
                    float th = 1.0f - 2.0f * __builtin_amdgcn_rcpf(e + 1.0f);  // tanh, inf-safe
                    p += th * u_r[ntl];
                }
                p = dpp_add<0xB1>(p);   // xor 1
                p = dpp_add<0x4E>(p);   // xor 2
                p = dpp_add<0x141>(p);  // row_half_mirror
                p = dpp_add<0x140>(p);  // row_mirror -> full 16-lane sum
                if (lm == 0) wpart[wave][m * 16 + lk * 4 + reg] = p;
            }
        }
        bar_lds();

        // ---- combine wave partials, exp; accumulate denominator in regs ----
        if (tid < TM) {   // wave 0
            float z  = wpart[0][tid] + wpart[1][tid] + wpart[2][tid] + wpart[3][tid];
            float wv = __expf(z);
            wlds[tid] = wv;
            sreg += wv;
        }
        bar_lds();

        // ---- pooling: accumulate into persistent vacc ----
#pragma unroll
        for (int i = 0; i < 8; ++i) {
            const int t = tgrp * 8 + i;
            bf16x8 xv = *(const bf16x8*)(buf + ((t * 512 + dgrp * 16) ^ ((t & 7) << 4)));
            float wt = wlds[t];
#pragma unroll
            for (int j = 0; j < 8; ++j) vacc[j] += (float)xv[j] * wt;
        }
        // no barrier: next stash writes the OTHER buffer; wpart/wlds rewrites are
        // separated from this tile's reads by the next iteration's barriers.
    }

    // ---- epilogue: denominator ----
    if (tid < TM) {
        float ss = sreg;
#pragma unroll
        for (int off = 1; off < 64; off <<= 1) ss += __shfl_xor(ss, off);
        if (tid == 0) atomicAdd(&s[b], ss);
    }

    // ---- epilogue: numerator ----
#pragma unroll
    for (int j = 0; j < 8; ++j) vacc[j] += __shfl_xor(vacc[j], 32);
    if (lane < 32) {
        *(f32x4*)&fpart[wave][dgrp][0] = (f32x4){vacc[0], vacc[1], vacc[2], vacc[3]};
        *(f32x4*)&fpart[wave][dgrp][4] = (f32x4){vacc[4], vacc[5], vacc[6], vacc[7]};
    }
    __syncthreads();
    float r = fpart[0][tid >> 3][tid & 7] + fpart[1][tid >> 3][tid & 7]
            + fpart[2][tid >> 3][tid & 7] + fpart[3][tid >> 3][tid & 7];
    atomicAdd(&N[b * DDIM + tid], r);

    // ---- last block of this batch finalizes out[b][:] ----
    __syncthreads();
    if (tid == 0) {
        __threadfence();                       // N/s adds visible before cnt
        int old = atomicAdd(&cnt[b], 1);
        flag_lds = (old == 7);
        if (old == 7) sv_lds = atomicAdd(&s[b], 0.0f);   // coherent read
    }
    __syncthreads();
    if (flag_lds) {
        float nv = atomicAdd(&N[b * DDIM + tid], 0.0f);  // coherent read
        out[b * DDIM + tid] = nv / (sv_lds + EPSC);
    }
}

extern "C" void kernel_launch(void* const* d_in, const int* in_sizes, int n_in,
                              void* d_out, int out_size, void* d_ws, size_t ws_size,
                              hipStream_t stream) {
    const float* x    = (const float*)d_in[0];
    const float* W    = (const float*)d_in[1];
    const float* bias = (const float*)d_in[2];
    const float* u    = (const float*)d_in[3];
    float* out = (float*)d_out;

    char* ws = (char*)d_ws;
    float* N   = (float*)ws;
    float* s   = (float*)(ws + 65536);
    int*   cnt = (int*)(ws + 65792);

    hipMemsetAsync(ws, 0, 66048, stream);   // zero N, s, cnt (memset node in graph)
    attn_main<<<BATCH * TLEN / (TILES * TM), 256, 0, stream>>>(x, W, bias, u, N, s, cnt, out);
}